// Round 4
// baseline (325.952 us; speedup 1.0000x reference)
//
#include <hip/hip_runtime.h>
#include <hip/hip_bf16.h>

typedef __bf16 bf16x8 __attribute__((ext_vector_type(8)));
typedef __bf16 bf16x4 __attribute__((ext_vector_type(4)));
typedef float f32x4 __attribute__((ext_vector_type(4)));

#define NB 4
#define NS 2048
#define ND 1024
#define NH 16
#define NDH 64
#define NM (NB*NS)   // 8192

#define MFMA(a,b,c) __builtin_amdgcn_mfma_f32_16x16x32_bf16((a),(b),(c),0,0,0)

__device__ __forceinline__ void gload16(const void* g, void* l) {
    __builtin_amdgcn_global_load_lds(
        (const __attribute__((address_space(1))) void*)(g),
        (__attribute__((address_space(3))) void*)(l),
        16, 0, 0);
}

// ---------------- cast fp32 -> bf16, vectorized ----------------
__global__ __launch_bounds__(256) void cast4(const float* __restrict__ in,
                                             __bf16* __restrict__ out, int n) {
    int i = (blockIdx.x * 256 + threadIdx.x) * 4;
    if (i >= n) return;
    float4 v = *(const float4*)(in + i);
    bf16x4 o;
    o[0] = (__bf16)v.x; o[1] = (__bf16)v.y; o[2] = (__bf16)v.z; o[3] = (__bf16)v.w;
    *(bf16x4*)(out + i) = o;
}

// ---------------- 128x128 GEMM, A[M,K] * W[N,K]^T ----------------
// MODE 0: z=0 -> Q [B,H,S,Dh] (scaled by 1/8*log2e), z=1 -> K, z=2 -> V^T [B,H,Dh,S]
// MODE 1: C fp32 row-major [M,N]
template<int MODE>
__global__ __launch_bounds__(256) void gemm128(
    const __bf16* __restrict__ A,
    const __bf16* __restrict__ W0, const __bf16* __restrict__ W1,
    const __bf16* __restrict__ W2,
    __bf16* __restrict__ O0, __bf16* __restrict__ O1, __bf16* __restrict__ O2,
    float* __restrict__ Cf)
{
    __shared__ alignas(16) __bf16 As[128*32];
    __shared__ alignas(16) __bf16 Bs[128*32];

    const int tid  = threadIdx.x;
    const int wave = tid >> 6, lane = tid & 63;
    const int l16  = lane & 15, lq = lane >> 4;
    const int bm = blockIdx.x * 128;
    const int bn = blockIdx.y * 128;
    const int z  = (MODE == 0) ? blockIdx.z : 0;
    const __bf16* __restrict__ Bw =
        (MODE == 0) ? ((z == 0) ? W0 : (z == 1) ? W1 : W2) : W0;

    const int wr = (wave >> 1) * 64;
    const int wc = (wave & 1) * 64;

    f32x4 acc[4][4];
    #pragma unroll
    for (int i = 0; i < 4; i++)
        #pragma unroll
        for (int j = 0; j < 4; j++)
            acc[i][j] = (f32x4){0.f, 0.f, 0.f, 0.f};

    const int ch0 = tid, ch1 = tid + 256;
    const int r0 = ch0 >> 2, c0 = (ch0 & 3) * 8;
    const int r1 = ch1 >> 2, c1 = (ch1 & 3) * 8;

    for (int k0 = 0; k0 < ND; k0 += 32) {
        __syncthreads();
        gload16(A  + (size_t)(bm + r0) * ND + k0 + c0, As + ch0 * 8);
        gload16(Bw + (size_t)(bn + r0) * ND + k0 + c0, Bs + ch0 * 8);
        gload16(A  + (size_t)(bm + r1) * ND + k0 + c1, As + ch1 * 8);
        gload16(Bw + (size_t)(bn + r1) * ND + k0 + c1, Bs + ch1 * 8);
        __syncthreads();

        bf16x8 af[4], bf[4];
        #pragma unroll
        for (int i = 0; i < 4; i++) {
            af[i] = *(const bf16x8*)(As + (wr + i*16 + l16) * 32 + lq * 8);
            bf[i] = *(const bf16x8*)(Bs + (wc + i*16 + l16) * 32 + lq * 8);
        }
        #pragma unroll
        for (int i = 0; i < 4; i++)
            #pragma unroll
            for (int j = 0; j < 4; j++)
                acc[i][j] = MFMA(af[i], bf[j], acc[i][j]);
    }

    #pragma unroll
    for (int i = 0; i < 4; i++) {
        #pragma unroll
        for (int j = 0; j < 4; j++) {
            #pragma unroll
            for (int r = 0; r < 4; r++) {
                int row = bm + wr + i*16 + lq*4 + r;   // m index (b*S + s)
                int col = bn + wc + j*16 + l16;        // n index (d_out)
                float v = acc[i][j][r];
                if (MODE == 1) {
                    Cf[(size_t)row * ND + col] = v;
                } else {
                    if (z == 0) v *= 0.1803368801111204f;  // 1/8 * log2(e)
                    int b = row >> 11, s = row & 2047;
                    int h = col >> 6,  dh = col & 63;
                    if (z < 2) {
                        __bf16* dst = (z == 0) ? O0 : O1;
                        dst[(((size_t)b*NH + h)*NS + s)*NDH + dh] = (__bf16)v;
                    } else {
                        O2[(((size_t)b*NH + h)*NDH + dh)*NS + s] = (__bf16)v;
                    }
                }
            }
        }
    }
}

// ---------------- causal flash attention ----------------
// Folded-pair blocks: block (bh, pi) processes q-tiles {15-pi, pi} (128 rows each).
// Static double-buffered K/V staging (compile-time buffer indices so the
// compiler can disambiguate prefetch-writes from current-tile reads), swizzled
// LDS, scores in log2 units (scale folded into Q), defer-max online softmax.
__global__ __launch_bounds__(256) void attn128(
    const __bf16* __restrict__ Q, const __bf16* __restrict__ K,
    const __bf16* __restrict__ Vt, __bf16* __restrict__ Oa)
{
    __shared__ alignas(16) __bf16 Ks0[64*64];
    __shared__ alignas(16) __bf16 Ks1[64*64];
    __shared__ alignas(16) __bf16 Vs0[64*64];      // [d][kv]
    __shared__ alignas(16) __bf16 Vs1[64*64];
    __shared__ alignas(16) __bf16 Ps[4][32*64];    // per-wave [qrow][kv]

    const int tid  = threadIdx.x;
    const int wave = tid >> 6, lane = tid & 63;
    const int l16  = lane & 15, lq = lane >> 4;
    const int bh = blockIdx.x;                 // b*16 + h
    const int pi = blockIdx.y;                 // pair index 0..7

    // staging geometry: 512 chunks of 16B per buffer, source col pre-swizzled
    const int ch0 = tid, ch1 = tid + 256;
    const int kr0 = ch0 >> 3, kc0 = ((ch0 & 7) * 8) ^ ((kr0 & 7) << 3);
    const int kr1 = ch1 >> 3, kc1 = ((ch1 & 7) * 8) ^ ((kr1 & 7) << 3);
    const size_t kbase = (size_t)bh * NS * NDH;   // K  [bh][s][dh]
    const size_t vbase = (size_t)bh * NDH * NS;   // Vt [bh][dh][s]
    const int xs = (l16 & 7) << 3;                // read-side swizzle (elements)
    const int b = bh >> 4, h = bh & 15;

    #pragma unroll 1
    for (int pass = 0; pass < 2; ++pass) {
        const int qt = pass ? pi : (15 - pi);
        const int q0 = qt * 128;
        const int wq0 = q0 + wave * 32;
        const int nt = qt * 2 + 2;                 // always even

        // Q fragments (2 row-tiles x 2 k-chunks); Q pre-scaled by 1/8*log2e
        bf16x8 qf[2][2];
        #pragma unroll
        for (int qi = 0; qi < 2; qi++) {
            const __bf16* qrow = Q + ((size_t)bh * NS + wq0 + qi*16 + l16) * NDH;
            qf[qi][0] = *(const bf16x8*)(qrow + lq * 8);
            qf[qi][1] = *(const bf16x8*)(qrow + 32 + lq * 8);
        }

        f32x4 o[2][4];
        float mr[2][4], ls[2][4];
        #pragma unroll
        for (int qi = 0; qi < 2; qi++)
            #pragma unroll
            for (int j = 0; j < 4; j++) {
                o[qi][j] = (f32x4){0.f, 0.f, 0.f, 0.f};
                mr[qi][j] = -__builtin_inff(); ls[qi][j] = 0.f;
            }

        // protect LDS from previous pass's readers, then prime buffer 0
        __builtin_amdgcn_s_barrier();
        gload16(K  + kbase + (size_t)kr0 * NDH + kc0, Ks0 + ch0 * 8);
        gload16(Vt + vbase + (size_t)kr0 * NS  + kc0, Vs0 + ch0 * 8);
        gload16(K  + kbase + (size_t)kr1 * NDH + kc1, Ks1 ? (Ks0 + ch1 * 8) : nullptr);
        gload16(Vt + vbase + (size_t)kr1 * NS  + kc1, Vs0 + ch1 * 8);

#define ATT_BODY(KB, VB, KBN, VBN, T)                                          \
        {                                                                      \
            const int kv0 = (T) * 64;                                          \
            asm volatile("s_waitcnt vmcnt(0)" ::: "memory");                   \
            __builtin_amdgcn_s_barrier();                                      \
            const bool act = (kv0 <= wq0 + 31);                                \
            bf16x8 kf[4][2];                                                   \
            if (act) {                                                         \
                _Pragma("unroll")                                              \
                for (int ni = 0; ni < 4; ni++) {                               \
                    const __bf16* kp = (KB) + (ni*16 + l16) * 64;              \
                    kf[ni][0] = *(const bf16x8*)(kp + ((lq*8) ^ xs));          \
                    kf[ni][1] = *(const bf16x8*)(kp + ((32 + lq*8) ^ xs));     \
                }                                                              \
            }                                                                  \
            if ((T) + 1 < nt) {                                                \
                const int nv0 = kv0 + 64;                                      \
                gload16(K  + kbase + (size_t)(nv0 + kr0) * NDH + kc0, (KBN) + ch0 * 8); \
                gload16(Vt + vbase + (size_t)kr0 * NS + nv0 + kc0,    (VBN) + ch0 * 8); \
                gload16(K  + kbase + (size_t)(nv0 + kr1) * NDH + kc1, (KBN) + ch1 * 8); \
                gload16(Vt + vbase + (size_t)kr1 * NS + nv0 + kc1,    (VBN) + ch1 * 8); \
            }                                                                  \
            __builtin_amdgcn_sched_barrier(0);                                 \
            if (act) {                                                         \
                const bool diag = ((T) >= nt - 2);                             \
                _Pragma("unroll")                                              \
                for (int qi = 0; qi < 2; qi++) {                               \
                    f32x4 s[4];                                                \
                    __builtin_amdgcn_s_setprio(1);                             \
                    _Pragma("unroll")                                          \
                    for (int ni = 0; ni < 4; ni++) {                           \
                        f32x4 z = (f32x4){0.f, 0.f, 0.f, 0.f};                 \
                        z = MFMA(qf[qi][0], kf[ni][0], z);                     \
                        z = MFMA(qf[qi][1], kf[ni][1], z);                     \
                        s[ni] = z;                                             \
                    }                                                          \
                    __builtin_amdgcn_s_setprio(0);                             \
                    if (diag) {                                                \
                        _Pragma("unroll")                                      \
                        for (int ni = 0; ni < 4; ni++)                         \
                            _Pragma("unroll")                                  \
                            for (int r = 0; r < 4; r++) {                      \
                                int col = kv0 + ni*16 + l16;                   \
                                int row = wq0 + qi*16 + lq*4 + r;              \
                                if (col > row) s[ni][r] = -__builtin_inff();   \
                            }                                                  \
                    }                                                          \
                    float pm[4];                                               \
                    _Pragma("unroll")                                          \
                    for (int r = 0; r < 4; r++) {                              \
                        float tm = fmaxf(fmaxf(s[0][r], s[1][r]),              \
                                         fmaxf(s[2][r], s[3][r]));             \
                        tm = fmaxf(tm, __shfl_xor(tm, 1));                     \
                        tm = fmaxf(tm, __shfl_xor(tm, 2));                     \
                        tm = fmaxf(tm, __shfl_xor(tm, 4));                     \
                        tm = fmaxf(tm, __shfl_xor(tm, 8));                     \
                        pm[r] = tm;                                            \
                    }                                                          \
                    bool need = (pm[0] > mr[qi][0] + 8.f) |                    \
                                (pm[1] > mr[qi][1] + 8.f) |                    \
                                (pm[2] > mr[qi][2] + 8.f) |                    \
                                (pm[3] > mr[qi][3] + 8.f);                     \
                    if (__any(need)) {                                         \
                        _Pragma("unroll")                                      \
                        for (int r = 0; r < 4; r++) {                          \
                            float mnew = fmaxf(mr[qi][r], pm[r]);              \
                            float fac = exp2f(mr[qi][r] - mnew);               \
                            mr[qi][r] = mnew;                                  \
                            ls[qi][r] *= fac;                                  \
                            _Pragma("unroll")                                  \
                            for (int d = 0; d < 4; d++) o[qi][d][r] *= fac;    \
                        }                                                      \
                    }                                                          \
                    _Pragma("unroll")                                          \
                    for (int r = 0; r < 4; r++) {                              \
                        const int prow = qi*16 + lq*4 + r;                     \
                        __bf16* pp = &Ps[wave][prow * 64];                     \
                        const int pxs = (prow & 7) << 3;                       \
                        float psum = 0.f;                                      \
                        _Pragma("unroll")                                      \
                        for (int ni = 0; ni < 4; ni++) {                       \
                            float pv = exp2f(s[ni][r] - mr[qi][r]);            \
                            pp[(ni*16 + l16) ^ pxs] = (__bf16)pv;              \
                            psum += pv;                                        \
                        }                                                      \
                        ls[qi][r] += psum;                                     \
                    }                                                          \
                }                                                              \
                bf16x8 pa[2][2];                                               \
                _Pragma("unroll")                                              \
                for (int qi = 0; qi < 2; qi++) {                               \
                    const __bf16* pp = &Ps[wave][(qi*16 + l16) * 64];          \
                    pa[qi][0] = *(const bf16x8*)(pp + ((lq*8) ^ xs));          \
                    pa[qi][1] = *(const bf16x8*)(pp + ((32 + lq*8) ^ xs));     \
                }                                                              \
                __builtin_amdgcn_s_setprio(1);                                 \
                _Pragma("unroll")                                              \
                for (int d = 0; d < 4; d++) {                                  \
                    const __bf16* vp = (VB) + (d*16 + l16) * 64;               \
                    bf16x8 vb0 = *(const bf16x8*)(vp + ((lq*8) ^ xs));         \
                    bf16x8 vb1 = *(const bf16x8*)(vp + ((32 + lq*8) ^ xs));    \
                    _Pragma("unroll")                                          \
                    for (int qi = 0; qi < 2; qi++) {                           \
                        o[qi][d] = MFMA(pa[qi][0], vb0, o[qi][d]);             \
                        o[qi][d] = MFMA(pa[qi][1], vb1, o[qi][d]);             \
                    }                                                          \
                }                                                              \
                __builtin_amdgcn_s_setprio(0);                                 \
            }                                                                  \
        }

        #pragma unroll 1
        for (int t = 0; t < nt; t += 2) {
            ATT_BODY(Ks0, Vs0, Ks1, Vs1, t)
            ATT_BODY(Ks1, Vs1, Ks0, Vs0, t + 1)
        }
#undef ATT_BODY

        // finalize: full row-sum and normalize
        #pragma unroll
        for (int qi = 0; qi < 2; qi++)
            #pragma unroll
            for (int r = 0; r < 4; r++) {
                float t = ls[qi][r];
                t += __shfl_xor(t, 1); t += __shfl_xor(t, 2);
                t += __shfl_xor(t, 4); t += __shfl_xor(t, 8);
                float inv = 1.f / t;
                int srow = wq0 + qi*16 + lq*4 + r;
                #pragma unroll
                for (int d = 0; d < 4; d++)
                    Oa[((size_t)b * NS + srow) * ND + h*64 + d*16 + l16] =
                        (__bf16)(o[qi][d][r] * inv);
            }
    }
}

extern "C" void kernel_launch(void* const* d_in, const int* in_sizes, int n_in,
                              void* d_out, int out_size, void* d_ws, size_t ws_size,
                              hipStream_t stream) {
    const float* x  = (const float*)d_in[0];
    const float* wq = (const float*)d_in[1];
    const float* wk = (const float*)d_in[2];
    const float* wv = (const float*)d_in[3];
    const float* wo = (const float*)d_in[4];
    char* ws = (char*)d_ws;

    __bf16* xb  = (__bf16*)(ws);                      // 16 MB  [M,K]
    __bf16* wqb = (__bf16*)(ws + (16ull << 20));      //  2 MB
    __bf16* wkb = (__bf16*)(ws + (18ull << 20));
    __bf16* wvb = (__bf16*)(ws + (20ull << 20));
    __bf16* wob = (__bf16*)(ws + (22ull << 20));
    __bf16* Qb  = (__bf16*)(ws + (24ull << 20));      // 16 MB [B,H,S,Dh]
    __bf16* Kb  = (__bf16*)(ws + (40ull << 20));      // 16 MB [B,H,S,Dh]
    __bf16* Vtb = (__bf16*)(ws + (56ull << 20));      // 16 MB [B,H,Dh,S]
    __bf16* Ab  = (__bf16*)(ws + (72ull << 20));      // 16 MB [B,S,D]
    float* out  = (float*)d_out;

    cast4<<<dim3(NM * ND / 1024), 256, 0, stream>>>(x,  xb,  NM * ND);
    cast4<<<dim3(ND * ND / 1024), 256, 0, stream>>>(wq, wqb, ND * ND);
    cast4<<<dim3(ND * ND / 1024), 256, 0, stream>>>(wk, wkb, ND * ND);
    cast4<<<dim3(ND * ND / 1024), 256, 0, stream>>>(wv, wvb, ND * ND);
    cast4<<<dim3(ND * ND / 1024), 256, 0, stream>>>(wo, wob, ND * ND);

    gemm128<0><<<dim3(NM/128, ND/128, 3), 256, 0, stream>>>(
        xb, wqb, wkb, wvb, Qb, Kb, Vtb, nullptr);

    attn128<<<dim3(NB*NH, 8), 256, 0, stream>>>(Qb, Kb, Vtb, Ab);

    gemm128<1><<<dim3(NM/128, ND/128), 256, 0, stream>>>(
        Ab, wob, nullptr, nullptr, nullptr, nullptr, nullptr, out);
}

// Round 5
// 251.137 us; speedup vs baseline: 1.2979x; 1.2979x over previous
//
#include <hip/hip_runtime.h>
#include <hip/hip_bf16.h>

typedef __bf16 bf16x8 __attribute__((ext_vector_type(8)));
typedef __bf16 bf16x4 __attribute__((ext_vector_type(4)));
typedef float f32x4 __attribute__((ext_vector_type(4)));

#define NB 4
#define NS 2048
#define ND 1024
#define NH 16
#define NDH 64
#define NM (NB*NS)   // 8192

#define MFMA(a,b,c) __builtin_amdgcn_mfma_f32_16x16x32_bf16((a),(b),(c),0,0,0)

__device__ __forceinline__ void gload16(const void* g, void* l) {
    __builtin_amdgcn_global_load_lds(
        (const __attribute__((address_space(1))) void*)(g),
        (__attribute__((address_space(3))) void*)(l),
        16, 0, 0);
}

// ---------------- cast fp32 -> bf16, vectorized ----------------
__global__ __launch_bounds__(256) void cast4(const float* __restrict__ in,
                                             __bf16* __restrict__ out, int n) {
    int i = (blockIdx.x * 256 + threadIdx.x) * 4;
    if (i >= n) return;
    float4 v = *(const float4*)(in + i);
    bf16x4 o;
    o[0] = (__bf16)v.x; o[1] = (__bf16)v.y; o[2] = (__bf16)v.z; o[3] = (__bf16)v.w;
    *(bf16x4*)(out + i) = o;
}

// ---------------- 128x128 GEMM, A[M,K] * W[N,K]^T ----------------
// MODE 0: z=0 -> Q [B,H,S,Dh] (scaled by 1/8*log2e), z=1 -> K, z=2 -> V^T [B,H,Dh,S]
// MODE 1: C fp32 row-major [M,N]
template<int MODE>
__global__ __launch_bounds__(256) void gemm128(
    const __bf16* __restrict__ A,
    const __bf16* __restrict__ W0, const __bf16* __restrict__ W1,
    const __bf16* __restrict__ W2,
    __bf16* __restrict__ O0, __bf16* __restrict__ O1, __bf16* __restrict__ O2,
    float* __restrict__ Cf)
{
    __shared__ alignas(16) __bf16 As[128*32];
    __shared__ alignas(16) __bf16 Bs[128*32];

    const int tid  = threadIdx.x;
    const int wave = tid >> 6, lane = tid & 63;
    const int l16  = lane & 15, lq = lane >> 4;
    const int bm = blockIdx.x * 128;
    const int bn = blockIdx.y * 128;
    const int z  = (MODE == 0) ? blockIdx.z : 0;
    const __bf16* __restrict__ Bw =
        (MODE == 0) ? ((z == 0) ? W0 : (z == 1) ? W1 : W2) : W0;

    const int wr = (wave >> 1) * 64;
    const int wc = (wave & 1) * 64;

    f32x4 acc[4][4];
    #pragma unroll
    for (int i = 0; i < 4; i++)
        #pragma unroll
        for (int j = 0; j < 4; j++)
            acc[i][j] = (f32x4){0.f, 0.f, 0.f, 0.f};

    const int ch0 = tid, ch1 = tid + 256;
    const int r0 = ch0 >> 2, c0 = (ch0 & 3) * 8;
    const int r1 = ch1 >> 2, c1 = (ch1 & 3) * 8;

    for (int k0 = 0; k0 < ND; k0 += 32) {
        __syncthreads();
        gload16(A  + (size_t)(bm + r0) * ND + k0 + c0, As + ch0 * 8);
        gload16(Bw + (size_t)(bn + r0) * ND + k0 + c0, Bs + ch0 * 8);
        gload16(A  + (size_t)(bm + r1) * ND + k0 + c1, As + ch1 * 8);
        gload16(Bw + (size_t)(bn + r1) * ND + k0 + c1, Bs + ch1 * 8);
        __syncthreads();

        bf16x8 af[4], bf[4];
        #pragma unroll
        for (int i = 0; i < 4; i++) {
            af[i] = *(const bf16x8*)(As + (wr + i*16 + l16) * 32 + lq * 8);
            bf[i] = *(const bf16x8*)(Bs + (wc + i*16 + l16) * 32 + lq * 8);
        }
        #pragma unroll
        for (int i = 0; i < 4; i++)
            #pragma unroll
            for (int j = 0; j < 4; j++)
                acc[i][j] = MFMA(af[i], bf[j], acc[i][j]);
    }

    #pragma unroll
    for (int i = 0; i < 4; i++) {
        #pragma unroll
        for (int j = 0; j < 4; j++) {
            #pragma unroll
            for (int r = 0; r < 4; r++) {
                int row = bm + wr + i*16 + lq*4 + r;   // m index (b*S + s)
                int col = bn + wc + j*16 + l16;        // n index (d_out)
                float v = acc[i][j][r];
                if (MODE == 1) {
                    Cf[(size_t)row * ND + col] = v;
                } else {
                    if (z == 0) v *= 0.1803368801111204f;  // 1/8 * log2(e)
                    int b = row >> 11, s = row & 2047;
                    int h = col >> 6,  dh = col & 63;
                    if (z < 2) {
                        __bf16* dst = (z == 0) ? O0 : O1;
                        dst[(((size_t)b*NH + h)*NS + s)*NDH + dh] = (__bf16)v;
                    } else {
                        O2[(((size_t)b*NH + h)*NDH + dh)*NS + s] = (__bf16)v;
                    }
                }
            }
        }
    }
}

// ---------------- causal flash attention: barrier-free, wave-independent ----
// Each wave owns a pair of 32-row q-blocks {63-p, p}; K/V fragments are read
// straight from global (L2-resident: 512 KB per head); only LDS use is the
// wave-private P relayout buffer. No __syncthreads / s_barrier anywhere.
// Q pre-scaled by 1/8*log2(e); scores in log2 units; defer-max online softmax.
__global__ __launch_bounds__(256, 2) void attn_wv(
    const __bf16* __restrict__ Q, const __bf16* __restrict__ K,
    const __bf16* __restrict__ Vt, __bf16* __restrict__ Oa)
{
    __shared__ alignas(16) __bf16 Ps[4][32*64];   // per-wave private 4 KB

    const int tid  = threadIdx.x;
    const int wave = tid >> 6, lane = tid & 63;
    const int l16  = lane & 15, lq = lane >> 4;

    // co-locate all 8 blocks of a bh-group on one XCD (hw XCD = blockIdx%8)
    const int wid0 = blockIdx.x;
    const int wid  = (wid0 & 7) * 64 + (wid0 >> 3);   // bijective, 512 blocks
    const int task = wid * 4 + wave;                  // 2048 wave-tasks
    const int bh   = task >> 5;                       // 0..63 (b*16+h)
    const int p    = task & 31;                       // pair index 0..31
    const int b = bh >> 4, h = bh & 15;
    const size_t qkb = (size_t)bh * NS * NDH;         // Q,K  [bh][s][dh]
    const size_t vbb = (size_t)bh * NDH * NS;         // Vt   [bh][dh][s]
    const int xs = (l16 & 7) << 3;
    __bf16* Pw = Ps[wave];

    #pragma unroll 1
    for (int half = 0; half < 2; ++half) {
        const int j  = half ? p : (63 - p);           // 32-row q-block index
        const int q0 = j * 32;
        const int ntk = (j >> 1) + 1;                 // # of 64-wide kv tiles

        // Q fragments (2 row-tiles x 2 k-chunks)
        bf16x8 qf[2][2];
        #pragma unroll
        for (int qi = 0; qi < 2; qi++) {
            const __bf16* qr = Q + qkb + (size_t)(q0 + qi*16 + l16) * NDH;
            qf[qi][0] = *(const bf16x8*)(qr + lq * 8);
            qf[qi][1] = *(const bf16x8*)(qr + 32 + lq * 8);
        }

        f32x4 o[2][4];
        float mr[2][4], ls[2][4];
        #pragma unroll
        for (int qi = 0; qi < 2; qi++)
            #pragma unroll
            for (int d = 0; d < 4; d++) {
                o[qi][d] = (f32x4){0.f, 0.f, 0.f, 0.f};
                mr[qi][d] = -__builtin_inff(); ls[qi][d] = 0.f;
            }

        #pragma unroll 1
        for (int t = 0; t < ntk; ++t) {
            const int kv0 = t * 64;

            // K fragments straight from global (A-frag: l16 = kv row)
            bf16x8 kf[4][2];
            #pragma unroll
            for (int ni = 0; ni < 4; ni++) {
                const __bf16* kp = K + qkb + (size_t)(kv0 + ni*16 + l16) * NDH;
                kf[ni][0] = *(const bf16x8*)(kp + lq * 8);
                kf[ni][1] = *(const bf16x8*)(kp + 32 + lq * 8);
            }
            // V fragments straight from global (B-frag: l16 = d row)
            bf16x8 vb[4][2];
            #pragma unroll
            for (int d = 0; d < 4; d++) {
                const __bf16* vp = Vt + vbb + (size_t)(d*16 + l16) * NS + kv0;
                vb[d][0] = *(const bf16x8*)(vp + lq * 8);
                vb[d][1] = *(const bf16x8*)(vp + 32 + lq * 8);
            }

            const bool diag = (t == ntk - 1);

            #pragma unroll
            for (int qi = 0; qi < 2; qi++) {
                f32x4 s[4];
                __builtin_amdgcn_s_setprio(1);
                #pragma unroll
                for (int ni = 0; ni < 4; ni++) {
                    f32x4 z = (f32x4){0.f, 0.f, 0.f, 0.f};
                    z = MFMA(qf[qi][0], kf[ni][0], z);
                    z = MFMA(qf[qi][1], kf[ni][1], z);
                    s[ni] = z;
                }
                __builtin_amdgcn_s_setprio(0);

                if (diag) {
                    #pragma unroll
                    for (int ni = 0; ni < 4; ni++)
                        #pragma unroll
                        for (int r = 0; r < 4; r++) {
                            int col = kv0 + ni*16 + l16;
                            int row = q0 + qi*16 + lq*4 + r;
                            if (col > row) s[ni][r] = -__builtin_inff();
                        }
                }

                // row maxes (row q = lq*4+r, spread over l16 lanes)
                float pm[4];
                #pragma unroll
                for (int r = 0; r < 4; r++) {
                    float tm = fmaxf(fmaxf(s[0][r], s[1][r]), fmaxf(s[2][r], s[3][r]));
                    tm = fmaxf(tm, __shfl_xor(tm, 1));
                    tm = fmaxf(tm, __shfl_xor(tm, 2));
                    tm = fmaxf(tm, __shfl_xor(tm, 4));
                    tm = fmaxf(tm, __shfl_xor(tm, 8));
                    pm[r] = tm;
                }
                bool need = (pm[0] > mr[qi][0] + 8.f) | (pm[1] > mr[qi][1] + 8.f) |
                            (pm[2] > mr[qi][2] + 8.f) | (pm[3] > mr[qi][3] + 8.f);
                if (__any(need)) {
                    #pragma unroll
                    for (int r = 0; r < 4; r++) {
                        float mnew = fmaxf(mr[qi][r], pm[r]);
                        float fac = exp2f(mr[qi][r] - mnew);
                        mr[qi][r] = mnew;
                        ls[qi][r] *= fac;
                        #pragma unroll
                        for (int d = 0; d < 4; d++) o[qi][d][r] *= fac;
                    }
                }
                #pragma unroll
                for (int r = 0; r < 4; r++) {
                    const int prow = qi*16 + lq*4 + r;
                    __bf16* pp = Pw + prow * 64;
                    const int pxs = (prow & 7) << 3;
                    float psum = 0.f;
                    #pragma unroll
                    for (int ni = 0; ni < 4; ni++) {
                        float pv = exp2f(s[ni][r] - mr[qi][r]);
                        pp[(ni*16 + l16) ^ pxs] = (__bf16)pv;
                        psum += pv;
                    }
                    ls[qi][r] += psum;
                }
            }

            // P relayout (wave-private; compiler inserts the lgkmcnt)
            bf16x8 pa[2][2];
            #pragma unroll
            for (int qi = 0; qi < 2; qi++) {
                const __bf16* pp = Pw + (qi*16 + l16) * 64;
                pa[qi][0] = *(const bf16x8*)(pp + ((lq*8) ^ xs));
                pa[qi][1] = *(const bf16x8*)(pp + ((32 + lq*8) ^ xs));
            }
            __builtin_amdgcn_s_setprio(1);
            #pragma unroll
            for (int d = 0; d < 4; d++)
                #pragma unroll
                for (int qi = 0; qi < 2; qi++) {
                    o[qi][d] = MFMA(pa[qi][0], vb[d][0], o[qi][d]);
                    o[qi][d] = MFMA(pa[qi][1], vb[d][1], o[qi][d]);
                }
            __builtin_amdgcn_s_setprio(0);
        }

        // finalize: full row-sum and normalize
        #pragma unroll
        for (int qi = 0; qi < 2; qi++)
            #pragma unroll
            for (int r = 0; r < 4; r++) {
                float t = ls[qi][r];
                t += __shfl_xor(t, 1); t += __shfl_xor(t, 2);
                t += __shfl_xor(t, 4); t += __shfl_xor(t, 8);
                float inv = 1.f / t;
                int srow = q0 + qi*16 + lq*4 + r;
                #pragma unroll
                for (int d = 0; d < 4; d++)
                    Oa[((size_t)b * NS + srow) * ND + h*64 + d*16 + l16] =
                        (__bf16)(o[qi][d][r] * inv);
            }
    }
}

extern "C" void kernel_launch(void* const* d_in, const int* in_sizes, int n_in,
                              void* d_out, int out_size, void* d_ws, size_t ws_size,
                              hipStream_t stream) {
    const float* x  = (const float*)d_in[0];
    const float* wq = (const float*)d_in[1];
    const float* wk = (const float*)d_in[2];
    const float* wv = (const float*)d_in[3];
    const float* wo = (const float*)d_in[4];
    char* ws = (char*)d_ws;

    __bf16* xb  = (__bf16*)(ws);                      // 16 MB  [M,K]
    __bf16* wqb = (__bf16*)(ws + (16ull << 20));      //  2 MB
    __bf16* wkb = (__bf16*)(ws + (18ull << 20));
    __bf16* wvb = (__bf16*)(ws + (20ull << 20));
    __bf16* wob = (__bf16*)(ws + (22ull << 20));
    __bf16* Qb  = (__bf16*)(ws + (24ull << 20));      // 16 MB [B,H,S,Dh]
    __bf16* Kb  = (__bf16*)(ws + (40ull << 20));      // 16 MB [B,H,S,Dh]
    __bf16* Vtb = (__bf16*)(ws + (56ull << 20));      // 16 MB [B,H,Dh,S]
    __bf16* Ab  = (__bf16*)(ws + (72ull << 20));      // 16 MB [B,S,D]
    float* out  = (float*)d_out;

    cast4<<<dim3(NM * ND / 1024), 256, 0, stream>>>(x,  xb,  NM * ND);
    cast4<<<dim3(ND * ND / 1024), 256, 0, stream>>>(wq, wqb, ND * ND);
    cast4<<<dim3(ND * ND / 1024), 256, 0, stream>>>(wk, wkb, ND * ND);
    cast4<<<dim3(ND * ND / 1024), 256, 0, stream>>>(wv, wvb, ND * ND);
    cast4<<<dim3(ND * ND / 1024), 256, 0, stream>>>(wo, wob, ND * ND);

    gemm128<0><<<dim3(NM/128, ND/128, 3), 256, 0, stream>>>(
        xb, wqb, wkb, wvb, Qb, Kb, Vtb, nullptr);

    attn_wv<<<dim3(512), 256, 0, stream>>>(Qb, Kb, Vtb, Ab);

    gemm128<1><<<dim3(NM/128, ND/128), 256, 0, stream>>>(
        Ab, wob, nullptr, nullptr, nullptr, nullptr, nullptr, out);
}